// Round 9
// baseline (506.016 us; speedup 1.0000x reference)
//
#include <hip/hip_runtime.h>
#include <math.h>

#define NH 10
#define NI 1152
#define NW 16
#define NS 8
#define NK 9    // i's per thread: NI / 128
#define NG 2    // b's per block (W reuse factor)

// Quad-lane butterfly add via DPP quad_perm (pure VALU, no DS pipe).
// 0xB1 = perm(1,0,3,2) = xor 1 ; 0x4E = perm(2,3,0,1) = xor 2.
template<int CTRL>
__device__ __forceinline__ float dpp_add(float v) {
    union { float f; int i; } a, r;
    a.f = v;
    r.i = __builtin_amdgcn_update_dpp(a.i, a.i, CTRL, 0xF, 0xF, true);
    return v + r.f;
}

// One block = 512 threads = one (b-pair, h). Thread (wq=tid&3, il=tid>>2) owns
// u[g][w][i], g=0,1, w in {wq,wq+4,wq+8,wq+12}, i in {il, il+128, ..., il+1024}.
// G=2 b-batching: each W line loaded ONCE serves both b's -> halves the
// L2->L1 stream (round-8 diagnosis: pinned at ~100us by W delivery, not waves:
// occupancy 22->41->61% left dur flat at ~25% VALUBusy).
// Routing logits are linear in u (b0 = 0): b_i^(r) = u_i . vacc.
// Softmax without max-subtraction (|d| <= ~44 -> e^44 ~ 1e19, safe in f32).
__global__ __launch_bounds__(512, 4)
void digitcaps_kernel(const float* __restrict__ x,
                      const float* __restrict__ Wc,
                      float* __restrict__ out)
{
    __shared__ float red3[NG][8][NW];   // per-wave partial s_w
    __shared__ float redE[NG][8];       // per-wave partial softmax denom
    __shared__ float vacc_sh[NG][NW];   // accumulated v per g

    const int tid  = threadIdx.x;
    const int wq   = tid & 3;       // quad lane -> w = 4j + wq
    const int il   = tid >> 2;      // 0..127 -> i = 128k + il
    const int lane = tid & 63;
    const int wid  = tid >> 6;      // wave 0..7

    const int h  = blockIdx.x >> 7; // grid = 10 h * 128 pairs, h-major
    const int bp = blockIdx.x & 127;
    const int b0 = bp * 2;

    const float* xa = x  + (size_t)b0 * (NI * NS);
    const float* xb = xa + (NI * NS);
    const float* Wh = Wc + (size_t)h * ((size_t)NI * NW * NS);

    float u[NG][4][NK];   // u[g][j][k] = u_g[4j+wq][128k+il], all in registers

    #pragma unroll
    for (int k = 0; k < NK; ++k) {
        const int i = k * 128 + il;
        const float4* xpa = reinterpret_cast<const float4*>(xa + (size_t)i * NS);
        const float4* xpb = reinterpret_cast<const float4*>(xb + (size_t)i * NS);
        const float4 a0 = xpa[0], a1 = xpa[1];    // same addr across quad
        const float4 b0v = xpb[0], b1v = xpb[1];
        #pragma unroll
        for (int j = 0; j < 4; ++j) {
            const float4* wp = reinterpret_cast<const float4*>(
                Wh + ((size_t)i * NW + 4 * j + wq) * NS);   // quad covers 128B
            const float4 w0 = wp[0], w1 = wp[1];            // loaded ONCE for both b's
            u[0][j][k] = w0.x*a0.x + w0.y*a0.y + w0.z*a0.z + w0.w*a0.w
                       + w1.x*a1.x + w1.y*a1.y + w1.z*a1.z + w1.w*a1.w;
            u[1][j][k] = w0.x*b0v.x + w0.y*b0v.y + w0.z*b0v.z + w0.w*b0v.w
                       + w1.x*b1v.x + w1.y*b1v.y + w1.z*b1v.z + w1.w*b1v.w;
        }
    }

    for (int r = 0; r < 3; ++r) {
        #pragma unroll
        for (int g = 0; g < NG; ++g) {
            float acc0 = 0.f, acc1 = 0.f, acc2 = 0.f, acc3 = 0.f, Ep = 0.f;
            if (r == 0) {
                #pragma unroll
                for (int k = 0; k < NK; ++k) {
                    acc0 += u[g][0][k]; acc1 += u[g][1][k];
                    acc2 += u[g][2][k]; acc3 += u[g][3][k];
                }
            } else {
                const float l2e = 1.44269504088896340736f;   // fold log2(e) into v
                const float v0 = vacc_sh[g][     wq] * l2e;
                const float v1 = vacc_sh[g][ 4 + wq] * l2e;
                const float v2 = vacc_sh[g][ 8 + wq] * l2e;
                const float v3 = vacc_sh[g][12 + wq] * l2e;
                #pragma unroll
                for (int k = 0; k < NK; ++k) {
                    float p = u[g][0][k]*v0 + u[g][1][k]*v1
                            + u[g][2][k]*v2 + u[g][3][k]*v3;
                    p = dpp_add<0xB1>(p);            // + xor1
                    p = dpp_add<0x4E>(p);            // + xor2 -> quad holds d_i*log2e
                    const float e = exp2f(p);
                    Ep += e;                          // identical across quad lanes
                    acc0 += e * u[g][0][k]; acc1 += e * u[g][1][k];
                    acc2 += e * u[g][2][k]; acc3 += e * u[g][3][k];
                }
            }
            // reduce over il within the wave (lane bits 2..5; quad lanes untouched)
            #pragma unroll
            for (int s = 4; s < 64; s <<= 1) {
                acc0 += __shfl_xor(acc0, s); acc1 += __shfl_xor(acc1, s);
                acc2 += __shfl_xor(acc2, s); acc3 += __shfl_xor(acc3, s);
                Ep   += __shfl_xor(Ep, s);
            }
            if (lane < 4) {            // lane == wq: holds full wave sums
                red3[g][wid][ 0 + lane] = acc0;
                red3[g][wid][ 4 + lane] = acc1;
                red3[g][wid][ 8 + lane] = acc2;
                red3[g][wid][12 + lane] = acc3;
                if (lane == 0) redE[g][wid] = Ep;
            }
        }
        __syncthreads();
        if (tid < 2 * NW) {            // 32 finalizers: g = tid>>4, w = tid&15
            const int g = tid >> 4, w2 = tid & 15;
            float s = 0.f, E = 0.f;
            #pragma unroll
            for (int q = 0; q < 8; ++q) { s += red3[g][q][w2]; E += redE[g][q]; }
            if (r == 0) E = (float)NI;   // redE counts each i exactly once
            s /= E;
            float sq = s * s;
            #pragma unroll
            for (int st = 1; st < 16; st <<= 1) sq += __shfl_xor(sq, st);
            const float f = sqrtf(sq) / (1.0f + sq);   // squash: ||s||/(1+||s||^2)
            const float v = s * f;
            if      (r == 0) vacc_sh[g][w2]  = v;
            else if (r == 1) vacc_sh[g][w2] += v;
            else out[((size_t)(b0 + g) * NH + h) * NW + w2] = v;
        }
        __syncthreads();
    }
}

extern "C" void kernel_launch(void* const* d_in, const int* in_sizes, int n_in,
                              void* d_out, int out_size, void* d_ws, size_t ws_size,
                              hipStream_t stream) {
    const float* x  = (const float*)d_in[0];
    const float* Wc = (const float*)d_in[1];
    float* out = (float*)d_out;
    digitcaps_kernel<<<dim3(NH * 128), dim3(512), 0, stream>>>(x, Wc, out);
}

// Round 11
// 293.916 us; speedup vs baseline: 1.7216x; 1.7216x over previous
//
#include <hip/hip_runtime.h>
#include <math.h>

#define NH 10
#define NI 1152
#define NW 16
#define NS 8
#define NK 9    // i's per thread: NI / 128
#define NG 2    // b's per block (W reuse factor)

// Quad-lane butterfly add via DPP quad_perm (pure VALU, no DS pipe).
// 0xB1 = perm(1,0,3,2) = xor 1 ; 0x4E = perm(2,3,0,1) = xor 2.
template<int CTRL>
__device__ __forceinline__ float dpp_add(float v) {
    union { float f; int i; } a, r;
    a.f = v;
    r.i = __builtin_amdgcn_update_dpp(a.i, a.i, CTRL, 0xF, 0xF, true);
    return v + r.f;
}

// One block = 512 threads = one (b-pair, h). Thread (wq=tid&3, il=tid>>2) owns
// u[g][w][i], g=0,1, w in {wq,wq+4,wq+8,wq+12}, i in {il, il+128, ..., il+1024}.
// G=2 b-batching: each W line loaded ONCE serves both b's -> halves L2 traffic
// AND doubles FMAs per load (1:16 stall:work, vs 1:8 in round 8).
// launch_bounds(512,2): reg cap 256. Round 9's (512,4) capped at 128 unified
// regs -> ~140 needed -> u[] spilled to scratch (WRITE_SIZE 809 MB, 457us).
// 1 block/CU (25% occ) is acceptable: rounds 7-8 showed occupancy 41->61%
// left dur flat; the binding constraint is the memory stall:work ratio.
// Routing logits are linear in u (b0 = 0): b_i^(r) = u_i . vacc.
// Softmax without max-subtraction (|d| <= ~44 -> e^44 ~ 1e19, safe in f32).
__global__ __launch_bounds__(512, 2)
void digitcaps_kernel(const float* __restrict__ x,
                      const float* __restrict__ Wc,
                      float* __restrict__ out)
{
    __shared__ float red3[NG][8][NW];   // per-wave partial s_w
    __shared__ float redE[NG][8];       // per-wave partial softmax denom
    __shared__ float vacc_sh[NG][NW];   // accumulated v per g

    const int tid  = threadIdx.x;
    const int wq   = tid & 3;       // quad lane -> w = 4j + wq
    const int il   = tid >> 2;      // 0..127 -> i = 128k + il
    const int lane = tid & 63;
    const int wid  = tid >> 6;      // wave 0..7

    const int h  = blockIdx.x >> 7; // grid = 10 h * 128 pairs, h-major
    const int bp = blockIdx.x & 127;
    const int b0 = bp * 2;

    const float* xa = x  + (size_t)b0 * (NI * NS);
    const float* xb = xa + (NI * NS);
    const float* Wh = Wc + (size_t)h * ((size_t)NI * NW * NS);

    float u[NG][4][NK];   // u[g][j][k] = u_g[4j+wq][128k+il], all in registers

    #pragma unroll
    for (int k = 0; k < NK; ++k) {
        const int i = k * 128 + il;
        const float4* xpa = reinterpret_cast<const float4*>(xa + (size_t)i * NS);
        const float4* xpb = reinterpret_cast<const float4*>(xb + (size_t)i * NS);
        const float4 a0 = xpa[0], a1 = xpa[1];    // same addr across quad
        const float4 b0v = xpb[0], b1v = xpb[1];
        #pragma unroll
        for (int j = 0; j < 4; ++j) {
            const float4* wp = reinterpret_cast<const float4*>(
                Wh + ((size_t)i * NW + 4 * j + wq) * NS);   // quad covers 128B
            const float4 w0 = wp[0], w1 = wp[1];            // loaded ONCE for both b's
            u[0][j][k] = w0.x*a0.x + w0.y*a0.y + w0.z*a0.z + w0.w*a0.w
                       + w1.x*a1.x + w1.y*a1.y + w1.z*a1.z + w1.w*a1.w;
            u[1][j][k] = w0.x*b0v.x + w0.y*b0v.y + w0.z*b0v.z + w0.w*b0v.w
                       + w1.x*b1v.x + w1.y*b1v.y + w1.z*b1v.z + w1.w*b1v.w;
        }
    }

    for (int r = 0; r < 3; ++r) {
        #pragma unroll
        for (int g = 0; g < NG; ++g) {
            float acc0 = 0.f, acc1 = 0.f, acc2 = 0.f, acc3 = 0.f, Ep = 0.f;
            if (r == 0) {
                #pragma unroll
                for (int k = 0; k < NK; ++k) {
                    acc0 += u[g][0][k]; acc1 += u[g][1][k];
                    acc2 += u[g][2][k]; acc3 += u[g][3][k];
                }
            } else {
                const float l2e = 1.44269504088896340736f;   // fold log2(e) into v
                const float v0 = vacc_sh[g][     wq] * l2e;
                const float v1 = vacc_sh[g][ 4 + wq] * l2e;
                const float v2 = vacc_sh[g][ 8 + wq] * l2e;
                const float v3 = vacc_sh[g][12 + wq] * l2e;
                #pragma unroll
                for (int k = 0; k < NK; ++k) {
                    float p = u[g][0][k]*v0 + u[g][1][k]*v1
                            + u[g][2][k]*v2 + u[g][3][k]*v3;
                    p = dpp_add<0xB1>(p);            // + xor1
                    p = dpp_add<0x4E>(p);            // + xor2 -> quad holds d_i*log2e
                    const float e = exp2f(p);
                    Ep += e;                          // identical across quad lanes
                    acc0 += e * u[g][0][k]; acc1 += e * u[g][1][k];
                    acc2 += e * u[g][2][k]; acc3 += e * u[g][3][k];
                }
            }
            // reduce over il within the wave (lane bits 2..5; quad lanes untouched)
            #pragma unroll
            for (int s = 4; s < 64; s <<= 1) {
                acc0 += __shfl_xor(acc0, s); acc1 += __shfl_xor(acc1, s);
                acc2 += __shfl_xor(acc2, s); acc3 += __shfl_xor(acc3, s);
                Ep   += __shfl_xor(Ep, s);
            }
            if (lane < 4) {            // lane == wq: holds full wave sums
                red3[g][wid][ 0 + lane] = acc0;
                red3[g][wid][ 4 + lane] = acc1;
                red3[g][wid][ 8 + lane] = acc2;
                red3[g][wid][12 + lane] = acc3;
                if (lane == 0) redE[g][wid] = Ep;
            }
        }
        __syncthreads();
        if (tid < 2 * NW) {            // 32 finalizers: g = tid>>4, w = tid&15
            const int g = tid >> 4, w2 = tid & 15;
            float s = 0.f, E = 0.f;
            #pragma unroll
            for (int q = 0; q < 8; ++q) { s += red3[g][q][w2]; E += redE[g][q]; }
            if (r == 0) E = (float)NI;   // redE counts each i exactly once
            s /= E;
            float sq = s * s;
            #pragma unroll
            for (int st = 1; st < 16; st <<= 1) sq += __shfl_xor(sq, st);
            const float f = sqrtf(sq) / (1.0f + sq);   // squash: ||s||/(1+||s||^2)
            const float v = s * f;
            if      (r == 0) vacc_sh[g][w2]  = v;
            else if (r == 1) vacc_sh[g][w2] += v;
            else out[((size_t)(b0 + g) * NH + h) * NW + w2] = v;
        }
        __syncthreads();
    }
}

extern "C" void kernel_launch(void* const* d_in, const int* in_sizes, int n_in,
                              void* d_out, int out_size, void* d_ws, size_t ws_size,
                              hipStream_t stream) {
    const float* x  = (const float*)d_in[0];
    const float* Wc = (const float*)d_in[1];
    float* out = (float*)d_out;
    digitcaps_kernel<<<dim3(NH * 128), dim3(512), 0, stream>>>(x, Wc, out);
}

// Round 12
// 223.871 us; speedup vs baseline: 2.2603x; 1.3129x over previous
//
#include <hip/hip_runtime.h>
#include <math.h>

#define NH 10
#define NI 1152
#define NW 16
#define NS 8
#define NK 9    // i's per thread: NI / 128
#define NG 2    // b's per block (W reuse factor)

// Quad-lane butterfly add via DPP quad_perm (pure VALU, no DS pipe).
// 0xB1 = perm(1,0,3,2) = xor 1 ; 0x4E = perm(2,3,0,1) = xor 2.
template<int CTRL>
__device__ __forceinline__ float dpp_add(float v) {
    union { float f; int i; } a, r;
    a.f = v;
    r.i = __builtin_amdgcn_update_dpp(a.i, a.i, CTRL, 0xF, 0xF, true);
    return v + r.f;
}

// One block = 512 threads = one (b-pair, h). Thread (wq=tid&3, il=tid>>2) owns
// u[g][w][i], g=0,1, w in {wq,wq+4,wq+8,wq+12}, i in {il, il+128, ..., il+1024}.
// G=2 b-batching: each W line loaded ONCE serves both b's -> halves L2 traffic
// AND doubles FMAs per load vs round 8.
// SPILL HISTORY: (512,4) -> VGPR 64, 809MB scratch; (512,2) -> VGPR 128,
// 407MB scratch. Fix: (512) unconstrained reg budget + "#pragma unroll 3"
// on the k-loop so the scheduler can't hoist all 108 float4 staging loads
// (full unroll inflated peak live regs; allocator spilled u[] to scratch).
// Routing logits are linear in u (b0 = 0): b_i^(r) = u_i . vacc.
// Softmax without max-subtraction (|d| <= ~44 -> e^44 ~ 1e19, safe in f32).
__global__ __launch_bounds__(512)
void digitcaps_kernel(const float* __restrict__ x,
                      const float* __restrict__ Wc,
                      float* __restrict__ out)
{
    __shared__ float red3[NG][8][NW];   // per-wave partial s_w
    __shared__ float redE[NG][8];       // per-wave partial softmax denom
    __shared__ float vacc_sh[NG][NW];   // accumulated v per g

    const int tid  = threadIdx.x;
    const int wq   = tid & 3;       // quad lane -> w = 4j + wq
    const int il   = tid >> 2;      // 0..127 -> i = 128k + il
    const int lane = tid & 63;
    const int wid  = tid >> 6;      // wave 0..7

    const int h  = blockIdx.x >> 7; // grid = 10 h * 128 pairs, h-major
    const int bp = blockIdx.x & 127;
    const int b0 = bp * 2;

    const float* xa = x  + (size_t)b0 * (NI * NS);
    const float* xb = xa + (NI * NS);
    const float* Wh = Wc + (size_t)h * ((size_t)NI * NW * NS);

    float u[NG][4][NK];   // u[g][j][k] = u_g[4j+wq][128k+il], all in registers

    #pragma unroll 3
    for (int k = 0; k < NK; ++k) {
        const int i = k * 128 + il;
        const float4* xpa = reinterpret_cast<const float4*>(xa + (size_t)i * NS);
        const float4* xpb = reinterpret_cast<const float4*>(xb + (size_t)i * NS);
        const float4 a0 = xpa[0], a1 = xpa[1];    // same addr across quad
        const float4 b0v = xpb[0], b1v = xpb[1];
        #pragma unroll
        for (int j = 0; j < 4; ++j) {
            const float4* wp = reinterpret_cast<const float4*>(
                Wh + ((size_t)i * NW + 4 * j + wq) * NS);   // quad covers 128B
            const float4 w0 = wp[0], w1 = wp[1];            // loaded ONCE for both b's
            u[0][j][k] = w0.x*a0.x + w0.y*a0.y + w0.z*a0.z + w0.w*a0.w
                       + w1.x*a1.x + w1.y*a1.y + w1.z*a1.z + w1.w*a1.w;
            u[1][j][k] = w0.x*b0v.x + w0.y*b0v.y + w0.z*b0v.z + w0.w*b0v.w
                       + w1.x*b1v.x + w1.y*b1v.y + w1.z*b1v.z + w1.w*b1v.w;
        }
    }

    for (int r = 0; r < 3; ++r) {
        #pragma unroll
        for (int g = 0; g < NG; ++g) {
            float acc0 = 0.f, acc1 = 0.f, acc2 = 0.f, acc3 = 0.f, Ep = 0.f;
            if (r == 0) {
                #pragma unroll
                for (int k = 0; k < NK; ++k) {
                    acc0 += u[g][0][k]; acc1 += u[g][1][k];
                    acc2 += u[g][2][k]; acc3 += u[g][3][k];
                }
            } else {
                const float l2e = 1.44269504088896340736f;   // fold log2(e) into v
                const float v0 = vacc_sh[g][     wq] * l2e;
                const float v1 = vacc_sh[g][ 4 + wq] * l2e;
                const float v2 = vacc_sh[g][ 8 + wq] * l2e;
                const float v3 = vacc_sh[g][12 + wq] * l2e;
                #pragma unroll
                for (int k = 0; k < NK; ++k) {
                    float p = u[g][0][k]*v0 + u[g][1][k]*v1
                            + u[g][2][k]*v2 + u[g][3][k]*v3;
                    p = dpp_add<0xB1>(p);            // + xor1
                    p = dpp_add<0x4E>(p);            // + xor2 -> quad holds d_i*log2e
                    const float e = exp2f(p);
                    Ep += e;                          // identical across quad lanes
                    acc0 += e * u[g][0][k]; acc1 += e * u[g][1][k];
                    acc2 += e * u[g][2][k]; acc3 += e * u[g][3][k];
                }
            }
            // reduce over il within the wave (lane bits 2..5; quad lanes untouched)
            #pragma unroll
            for (int s = 4; s < 64; s <<= 1) {
                acc0 += __shfl_xor(acc0, s); acc1 += __shfl_xor(acc1, s);
                acc2 += __shfl_xor(acc2, s); acc3 += __shfl_xor(acc3, s);
                Ep   += __shfl_xor(Ep, s);
            }
            if (lane < 4) {            // lane == wq: holds full wave sums
                red3[g][wid][ 0 + lane] = acc0;
                red3[g][wid][ 4 + lane] = acc1;
                red3[g][wid][ 8 + lane] = acc2;
                red3[g][wid][12 + lane] = acc3;
                if (lane == 0) redE[g][wid] = Ep;
            }
        }
        __syncthreads();
        if (tid < 2 * NW) {            // 32 finalizers: g = tid>>4, w = tid&15
            const int g = tid >> 4, w2 = tid & 15;
            float s = 0.f, E = 0.f;
            #pragma unroll
            for (int q = 0; q < 8; ++q) { s += red3[g][q][w2]; E += redE[g][q]; }
            if (r == 0) E = (float)NI;   // redE counts each i exactly once
            s /= E;
            float sq = s * s;
            #pragma unroll
            for (int st = 1; st < 16; st <<= 1) sq += __shfl_xor(sq, st);
            const float f = sqrtf(sq) / (1.0f + sq);   // squash: ||s||/(1+||s||^2)
            const float v = s * f;
            if      (r == 0) vacc_sh[g][w2]  = v;
            else if (r == 1) vacc_sh[g][w2] += v;
            else out[((size_t)(b0 + g) * NH + h) * NW + w2] = v;
        }
        __syncthreads();
    }
}

extern "C" void kernel_launch(void* const* d_in, const int* in_sizes, int n_in,
                              void* d_out, int out_size, void* d_ws, size_t ws_size,
                              hipStream_t stream) {
    const float* x  = (const float*)d_in[0];
    const float* Wc = (const float*)d_in[1];
    float* out = (float*)d_out;
    digitcaps_kernel<<<dim3(NH * 128), dim3(512), 0, stream>>>(x, Wc, out);
}